// Round 1
// 203.644 us; speedup vs baseline: 1.0441x; 1.0441x over previous
//
#include <hip/hip_runtime.h>
#include <hip/hip_bf16.h>
#include <cfloat>

// Problem constants (fixed by the reference file)
#define NN 4096
#define DD 256
#define MM 5
#define GG 4
#define K_TOT 30       // 20 intra + 10 inter
#define TGT_INTRA 32   // capture >= 32 intra candidates (need top-21 incl self)
#define TGT_INTER 24   // capture >= 24 inter candidates (need top-10)
#define CAND_CAP 64

typedef __attribute__((ext_vector_type(8))) short bf16x8;
typedef __attribute__((ext_vector_type(4))) float f32x4;

// async global->LDS, 16 B per lane; LDS dest = wave-uniform base + lane*16
__device__ __forceinline__ void async16(const void* g, void* l) {
    __builtin_amdgcn_global_load_lds((__attribute__((address_space(1))) void*)g,
                                     (__attribute__((address_space(3))) void*)l,
                                     16, 0, 0);
}

// ---------------------------------------------------------------------------
// Kernel 0: E fp32 -> bf16 (RNE). Selection-only precision; exact ordering
// comes from the fp64 rescore in select_rescore.
// ---------------------------------------------------------------------------
__global__ __launch_bounds__(256) void convert_bf16(const float* __restrict__ E,
                                                    ushort* __restrict__ Eb) {
    const int idx = blockIdx.x * 256 + threadIdx.x;
    const float4 f = ((const float4*)E)[idx];
    ushort4 h;
    {
        __hip_bfloat16 a = __float2bfloat16(f.x); h.x = *(ushort*)&a;
        __hip_bfloat16 b = __float2bfloat16(f.y); h.y = *(ushort*)&b;
        __hip_bfloat16 c = __float2bfloat16(f.z); h.z = *(ushort*)&c;
        __hip_bfloat16 d = __float2bfloat16(f.w); h.w = *(ushort*)&d;
    }
    ((ushort4*)Eb)[idx] = h;
}

// ---------------------------------------------------------------------------
// Kernel 0b: per-batch inter-mask bitmap. maskTab[g][j/64] bit (j%64) = 1 iff
// batch[j] != g. 2 KB total; replaces per-row batch reloads in select_rescore
// (cuts pass-1 bytes and transient VGPRs for the 64-VGPR occupancy target).
// ---------------------------------------------------------------------------
__global__ __launch_bounds__(256) void build_mask(const int* __restrict__ batch,
                                                  unsigned long long* __restrict__ maskTab) {
    const int j = blockIdx.x * 256 + threadIdx.x;
    const int b = batch[j];
    const int wv = j >> 6;
#pragma unroll
    for (int g = 0; g < GG; ++g) {
        const unsigned long long m = __ballot(b != g);
        if ((threadIdx.x & 63) == 0) maskTab[g * (NN / 64) + wv] = m;
    }
}

// ---------------------------------------------------------------------------
// Kernel 1: sim = Eb @ Eb^T via MFMA bf16 -> bf16 out. 128x128 tile, 4 waves
// (2x2 of 64x64), 16x16x32 MFMA, BK=32. global_load_lds width=16 staging
// into unpadded [128][32] with XOR chunk swizzle (2-way max = free).
// Epilogue staged in 4 chunks of 32 rows through the 16 KB A/B buffers.
// ---------------------------------------------------------------------------
__global__ __launch_bounds__(256) void gemm_bf16(const ushort* __restrict__ Eb,
                                                 ushort* __restrict__ simb) {
    __shared__ union {
        struct { ushort A[128 * 32]; ushort B[128 * 32]; } s;  // 8 KB + 8 KB
        ushort stage[32 * 136];                                // 8.7 KB epilogue
    } lds;

    const int t = threadIdx.x;
    const int w = t >> 6, lane = t & 63;
    const int quad = lane >> 4, mr = lane & 15;
    const int rowBase = blockIdx.y * 128, colBase = blockIdx.x * 128;
    const int waveRow = (w & 1) * 64, waveCol = (w >> 1) * 64;

    const int lrow = lane >> 2;              // 0..15 row within 16-row slab
    const int lslot = lane & 3;              // LDS chunk slot
    const int gchunk = lslot ^ ((lrow >> 1) & 3);  // swizzled global chunk

    f32x4 acc[4][4];
#pragma unroll
    for (int a = 0; a < 4; ++a)
#pragma unroll
        for (int b = 0; b < 4; ++b) acc[a][b] = (f32x4)(0.0f);

    for (int kc = 0; kc < DD; kc += 32) {
#pragma unroll
        for (int n = 0; n < 2; ++n) {
            const int r = w * 32 + n * 16 + lrow;  // (r>>1)&3 == (lrow>>1)&3
            const ushort* ga = Eb + (size_t)(rowBase + r) * DD + kc + gchunk * 8;
            const ushort* gb = Eb + (size_t)(colBase + r) * DD + kc + gchunk * 8;
            async16(ga, &lds.s.A[(w * 32 + n * 16) * 32]);
            async16(gb, &lds.s.B[(w * 32 + n * 16) * 32]);
        }
        __syncthreads();

        const int swzF = (mr >> 1) & 3;
        bf16x8 af[4], bfr[4];
#pragma unroll
        for (int rt = 0; rt < 4; ++rt)
            af[rt] = *(const bf16x8*)&lds.s.A[(waveRow + rt * 16 + mr) * 32 +
                                              ((quad ^ swzF) * 8)];
#pragma unroll
        for (int ct = 0; ct < 4; ++ct)
            bfr[ct] = *(const bf16x8*)&lds.s.B[(waveCol + ct * 16 + mr) * 32 +
                                               ((quad ^ swzF) * 8)];
#pragma unroll
        for (int rt = 0; rt < 4; ++rt)
#pragma unroll
            for (int ct = 0; ct < 4; ++ct)
                acc[rt][ct] = __builtin_amdgcn_mfma_f32_16x16x32_bf16(
                    af[rt], bfr[ct], acc[rt][ct], 0, 0, 0);
        __syncthreads();
    }

    // epilogue: 4 chunks of 32 tile-rows through the 8.7 KB stage buffer
#pragma unroll
    for (int c = 0; c < 4; ++c) {
        __syncthreads();  // stage free (K-loop done / prev copy done)
        if ((w & 1) == (c >> 1)) {
            const int rtBase = 2 * (c & 1);
#pragma unroll
            for (int r2 = 0; r2 < 2; ++r2) {
                const int rt = rtBase + r2;
#pragma unroll
                for (int ct = 0; ct < 4; ++ct)
#pragma unroll
                    for (int reg = 0; reg < 4; ++reg) {
                        __hip_bfloat16 hb = __float2bfloat16(acc[rt][ct][reg]);
                        const int lr2 = r2 * 16 + quad * 4 + reg;  // 0..31
                        lds.stage[lr2 * 136 + waveCol + ct * 16 + mr] = *(ushort*)&hb;
                    }
            }
        }
        __syncthreads();
#pragma unroll
        for (int it = 0; it < 2; ++it) {
            const int cid = t + it * 256;   // 0..511 (32 rows x 16 int4)
            const int row = cid >> 4;
            const int off = (cid & 15) * 8;
            *(int4*)(simb + (size_t)(rowBase + c * 32 + row) * NN + colBase + off) =
                *(const int4*)&lds.stage[row * 136 + off];
        }
    }
}

// ---------------------------------------------------------------------------
// Kernel 2: ONE ROW PER BLOCK, 128 threads (2 waves share the row).
// Occupancy redesign vs prior version: grid 4096 x 1-row blocks (was 1024 x
// 4-row); 16 wg/CU x 2 waves = 32 waves/CU (was ~8 effective). The two waves
// of a block process the SAME row -> zero barrier imbalance. 32 keys/lane in
// registers (16 packed u16x2, half the prior VGPR state), block-shared packed
// histogram (intra lo16 / inter hi16) -> exact 16-bit bf16-key threshold,
// candidate collect, fp64 rescore (128-wide, one pass), rank-based ordered
// output with intra/inter ranking split across the two waves.
// ---------------------------------------------------------------------------
__global__ __launch_bounds__(128, 8) void select_rescore(
        const ushort* __restrict__ sim,
        const float* __restrict__ E,
        const int* __restrict__ batch,
        const unsigned long long* __restrict__ maskTab,
        int* __restrict__ knn) {
    __shared__ unsigned histS[256];
    __shared__ unsigned subS[256];
    __shared__ int candIdxS[2][CAND_CAP];
    __shared__ double candValS[2][CAND_CAP];
    __shared__ int cntS[2];
    __shared__ int cbS[2];
    __shared__ unsigned remS[2];
    __shared__ unsigned thrS[2];

    const int t = threadIdx.x;
    const int w = t >> 6, lane = t & 63;
    const int i = blockIdx.x;
    const int bi = batch[i];

    histS[t] = 0u; histS[t + 128] = 0u;
    subS[t] = 0u;  subS[t + 128] = 0u;
    if (t < 2) cntS[t] = 0;
    __syncthreads();

    // ---- pass 1: load 32 elems/thread, build keys + inter-mask + histogram --
    // element j = c*1024 + t*8 + e  (16 B / thread per chunk: fully coalesced)
    unsigned kp[16];                 // packed sortable keys (2 per u32)
    unsigned interm = 0;             // bit (c*8+e) => batch differs
    {
        const ushort* sp = sim + (size_t)i * NN + t * 8;
        const unsigned long long* mp = maskTab + bi * (NN / 64) + (t >> 3);
        const int sh = (t & 7) * 8;
#pragma unroll
        for (int c = 0; c < 4; ++c) {
            const int4 sv = *(const int4*)(sp + c * 1024);
            const unsigned mb = (unsigned)(mp[c * 16] >> sh) & 0xFFu;
            interm |= mb << (c * 8);
            const unsigned uu[4] = {(unsigned)sv.x, (unsigned)sv.y,
                                    (unsigned)sv.z, (unsigned)sv.w};
#pragma unroll
            for (int p = 0; p < 4; ++p) {
                const unsigned u = uu[p];
                const unsigned sgn = u & 0x80008000u;
                // per-half monotone transform: pos: ^0x8000, neg: ^0xFFFF
                const unsigned k2 = u ^ (0x80008000u | ((sgn >> 15) * 0x7FFFu));
                kp[c * 4 + p] = k2;
                const unsigned m0 = (mb >> (2 * p)) & 1u;
                const unsigned m1 = (mb >> (2 * p + 1)) & 1u;
                atomicAdd(&histS[(k2 >> 8) & 0xFF], m0 ? 0x10000u : 1u);
                atomicAdd(&histS[k2 >> 24], m1 ? 0x10000u : 1u);
            }
        }
    }
    __syncthreads();

    // ---- pass 2: packed descending scan over coarse bins (redundant per
    // wave -- both waves compute identical values from shared hist) ----
    {
        const unsigned* hb = &histS[lane * 4];
        const unsigned s4 = hb[0] + hb[1] + hb[2] + hb[3];
        unsigned suf = s4;  // suffix-inclusive over lanes >= lane (higher bins)
#pragma unroll
        for (int off = 1; off < 64; off <<= 1) {
            const unsigned o = __shfl_down(suf, off);
            if (lane + off < 64) suf += o;
        }
        unsigned cum = suf - s4;  // count in bins above this lane's range
#pragma unroll
        for (int b = 3; b >= 0; --b) {
            const unsigned h = hb[b];
            const unsigned prev = cum;
            cum += h;
            if ((cum & 0xFFFFu) >= TGT_INTRA && (prev & 0xFFFFu) < TGT_INTRA) {
                cbS[0] = lane * 4 + b;
                remS[0] = TGT_INTRA - (prev & 0xFFFFu);
            }
            if ((cum >> 16) >= TGT_INTER && (prev >> 16) < TGT_INTER) {
                cbS[1] = lane * 4 + b;
                remS[1] = TGT_INTER - (prev >> 16);
            }
        }
    }
    __syncthreads();

    // ---- pass 2b: sub-histogram of crossing bins (low byte) ----
    {
        const int cb0 = cbS[0], cb1 = cbS[1];
#pragma unroll
        for (int c = 0; c < 4; ++c)
#pragma unroll
            for (int p = 0; p < 4; ++p) {
                const unsigned k2 = kp[c * 4 + p];
                const unsigned k0 = k2 & 0xFFFFu, k1 = k2 >> 16;
                const int m0 = (interm >> (c * 8 + 2 * p)) & 1;
                const int m1 = (interm >> (c * 8 + 2 * p + 1)) & 1;
                if ((int)(k0 >> 8) == (m0 ? cb1 : cb0))
                    atomicAdd(&subS[k0 & 0xFF], m0 ? 0x10000u : 1u);
                if ((int)(k1 >> 8) == (m1 ? cb1 : cb0))
                    atomicAdd(&subS[k1 & 0xFF], m1 ? 0x10000u : 1u);
            }
    }
    __syncthreads();

    // ---- pass 2c: scan sub-bins -> exact 16-bit thresholds (redundant) ----
    {
        const unsigned rI = remS[0], rT = remS[1];
        const int cb0 = cbS[0], cb1 = cbS[1];
        const unsigned* sb = &subS[lane * 4];
        const unsigned s4 = sb[0] + sb[1] + sb[2] + sb[3];
        unsigned suf = s4;
#pragma unroll
        for (int off = 1; off < 64; off <<= 1) {
            const unsigned o = __shfl_down(suf, off);
            if (lane + off < 64) suf += o;
        }
        unsigned cum = suf - s4;
#pragma unroll
        for (int b = 3; b >= 0; --b) {
            const unsigned h = sb[b];
            const unsigned prev = cum;
            cum += h;
            if ((cum & 0xFFFFu) >= rI && (prev & 0xFFFFu) < rI)
                thrS[0] = ((unsigned)cb0 << 8) | (unsigned)(lane * 4 + b);
            if ((cum >> 16) >= rT && (prev >> 16) < rT)
                thrS[1] = ((unsigned)cb1 << 8) | (unsigned)(lane * 4 + b);
        }
    }
    __syncthreads();

    // ---- pass 3: collect candidate indices ----
    {
        const unsigned thr0 = thrS[0], thr1 = thrS[1];
#pragma unroll
        for (int c = 0; c < 4; ++c)
#pragma unroll
            for (int p = 0; p < 4; ++p) {
                const unsigned k2 = kp[c * 4 + p];
                const unsigned k0 = k2 & 0xFFFFu, k1 = k2 >> 16;
                const int m0 = (interm >> (c * 8 + 2 * p)) & 1;
                const int m1 = (interm >> (c * 8 + 2 * p + 1)) & 1;
                if (k0 >= (m0 ? thr1 : thr0)) {
                    const int pos = atomicAdd(&cntS[m0], 1);
                    if (pos < CAND_CAP) candIdxS[m0][pos] = c * 1024 + t * 8 + 2 * p;
                }
                if (k1 >= (m1 ? thr1 : thr0)) {
                    const int pos = atomicAdd(&cntS[m1], 1);
                    if (pos < CAND_CAP) candIdxS[m1][pos] = c * 1024 + t * 8 + 2 * p + 1;
                }
            }
    }
    __syncthreads();

    // ---- pass 4: fp64 rescore, 128-wide (tot <= 128 -> one pass);
    // E[i] is block-uniform -> scalar loads ----
    const int c0 = min(cntS[0], CAND_CAP);
    const int c1 = min(cntS[1], CAND_CAP);
    {
        const int tot = c0 + c1;
        const float* ei = E + (size_t)i * DD;
        if (t < tot) {
            const int m = (t < c0) ? 0 : 1;
            const int s = m ? (t - c0) : t;
            const int j = candIdxS[m][s];
            const float* ej = E + (size_t)j * DD;
            double a0 = 0, a1 = 0, a2 = 0, a3 = 0;
#pragma unroll 8
            for (int k = 0; k < DD; k += 4) {
                const float4 e = *(const float4*)(ej + k);
                a0 = fma((double)ei[k + 0], (double)e.x, a0);
                a1 = fma((double)ei[k + 1], (double)e.y, a1);
                a2 = fma((double)ei[k + 2], (double)e.z, a2);
                a3 = fma((double)ei[k + 3], (double)e.w, a3);
            }
            candValS[m][s] = (a0 + a1) + (a2 + a3);
        }
    }
    __syncthreads();

    // ---- pass 5: rank-based ordered output (ties: lower index first);
    // wave 0 ranks intra, wave 1 ranks inter (parallel) ----
    if (w == 0) {
        if (lane < c0) {
            const double v = candValS[0][lane];
            const int idx = candIdxS[0][lane];
            int r = 0;
            for (int s = 0; s < c0; ++s) {
                const double o = candValS[0][s];
                const int oi = candIdxS[0][s];
                r += (o > v) || (o == v && oi < idx);
            }
            if (r >= 1 && r <= 20) knn[i * K_TOT + r - 1] = idx;  // rank0 = self
        }
    } else {
        if (lane < c1) {
            const double v = candValS[1][lane];
            const int idx = candIdxS[1][lane];
            int r = 0;
            for (int s = 0; s < c1; ++s) {
                const double o = candValS[1][s];
                const int oi = candIdxS[1][s];
                r += (o > v) || (o == v && oi < idx);
            }
            if (r < 10) knn[i * K_TOT + 20 + r] = idx;
        }
    }
}

// ---------------------------------------------------------------------------
// Kernel 3: mutuality + sparse locality scatter + all_close.
// ---------------------------------------------------------------------------
__global__ __launch_bounds__(256) void finalize_k(const int* __restrict__ knn,
                                                  const float* __restrict__ adj,
                                                  const int* __restrict__ cl,
                                                  float* __restrict__ out) {
    const int gid = blockIdx.x * 256 + threadIdx.x;
    if (gid >= NN * K_TOT) return;
    const int i = gid / K_TOT;
    const int j = knn[gid];

    bool mutual = false;
#pragma unroll
    for (int s = 0; s < K_TOT; ++s) mutual |= (knn[j * K_TOT + s] == i);

    if (mutual) out[(size_t)i * NN + j] = adj[(size_t)i * NN + j];

    bool ac = mutual;
    if (!ac) {
        bool alleq = true;
#pragma unroll
        for (int m = 0; m < MM; ++m) alleq &= (cl[m * NN + i] == cl[m * NN + j]);
        ac = alleq;
    }
    out[(size_t)NN * NN + gid] = ac ? 1.0f : 0.0f;
}

// ---------------------------------------------------------------------------
extern "C" void kernel_launch(void* const* d_in, const int* in_sizes, int n_in,
                              void* d_out, int out_size, void* d_ws, size_t ws_size,
                              hipStream_t stream) {
    const float* adj = (const float*)d_in[0];
    const float* enc = (const float*)d_in[1];
    const int* batch = (const int*)d_in[2];
    const int* cl = (const int*)d_in[3];
    float* out = (float*)d_out;

    const size_t simB = (size_t)NN * NN * sizeof(ushort);   // 33.6 MB
    const size_t ebB = (size_t)NN * DD * sizeof(ushort);    // 2.1 MB
    const size_t knnB = (size_t)NN * K_TOT * sizeof(int);   // 0.49 MB
    const size_t maskB = (size_t)GG * (NN / 64) * sizeof(unsigned long long); // 2 KB

    const dim3 gGrid(NN / 128, NN / 128);

    if (ws_size >= simB + ebB + knnB + maskB) {
        ushort* simb = (ushort*)d_ws;
        ushort* Eb = (ushort*)((char*)d_ws + simB);
        int* knn = (int*)((char*)d_ws + simB + ebB);
        unsigned long long* maskTab =
            (unsigned long long*)((char*)d_ws + simB + ebB + knnB);
        hipMemsetAsync(d_out, 0, (size_t)NN * NN * sizeof(float), stream);
        convert_bf16<<<NN * DD / 4 / 256, 256, 0, stream>>>(enc, Eb);
        build_mask<<<NN / 256, 256, 0, stream>>>(batch, maskTab);
        gemm_bf16<<<gGrid, 256, 0, stream>>>(Eb, simb);
        select_rescore<<<NN, 128, 0, stream>>>(simb, enc, batch, maskTab, knn);
        finalize_k<<<(NN * K_TOT + 255) / 256, 256, 0, stream>>>(knn, adj, cl, out);
    } else {
        // fallback: stage bf16 sims in the locality region of d_out, memset after
        ushort* simb = (ushort*)d_out;
        ushort* Eb = (ushort*)d_ws;
        int* knn = (int*)((char*)d_ws + ebB);
        unsigned long long* maskTab =
            (unsigned long long*)((char*)d_ws + ebB + knnB);
        convert_bf16<<<NN * DD / 4 / 256, 256, 0, stream>>>(enc, Eb);
        build_mask<<<NN / 256, 256, 0, stream>>>(batch, maskTab);
        gemm_bf16<<<gGrid, 256, 0, stream>>>(Eb, simb);
        select_rescore<<<NN, 128, 0, stream>>>(simb, enc, batch, maskTab, knn);
        hipMemsetAsync(d_out, 0, (size_t)NN * NN * sizeof(float), stream);
        finalize_k<<<(NN * K_TOT + 255) / 256, 256, 0, stream>>>(knn, adj, cl, out);
    }
}

// Round 2
// 201.656 us; speedup vs baseline: 1.0543x; 1.0099x over previous
//
#include <hip/hip_runtime.h>
#include <hip/hip_bf16.h>
#include <cfloat>

// Problem constants (fixed by the reference file)
#define NN 4096
#define DD 256
#define MM 5
#define GG 4
#define K_TOT 30       // 20 intra + 10 inter
#define TGT_INTRA 32   // capture >= 32 intra candidates (need top-21 incl self)
#define TGT_INTER 24   // capture >= 24 inter candidates (need top-10)
#define CAND_CAP 64

typedef __attribute__((ext_vector_type(8))) short bf16x8;
typedef __attribute__((ext_vector_type(4))) float f32x4;

// async global->LDS, 16 B per lane; LDS dest = wave-uniform base + lane*16
__device__ __forceinline__ void async16(const void* g, void* l) {
    __builtin_amdgcn_global_load_lds((__attribute__((address_space(1))) void*)g,
                                     (__attribute__((address_space(3))) void*)l,
                                     16, 0, 0);
}

// ---------------------------------------------------------------------------
// Kernel 0: E fp32 -> bf16 (RNE). Selection-only precision; exact ordering
// comes from the fp64 rescore in select_rescore.
// ---------------------------------------------------------------------------
__global__ __launch_bounds__(256) void convert_bf16(const float* __restrict__ E,
                                                    ushort* __restrict__ Eb) {
    const int idx = blockIdx.x * 256 + threadIdx.x;
    const float4 f = ((const float4*)E)[idx];
    ushort4 h;
    {
        __hip_bfloat16 a = __float2bfloat16(f.x); h.x = *(ushort*)&a;
        __hip_bfloat16 b = __float2bfloat16(f.y); h.y = *(ushort*)&b;
        __hip_bfloat16 c = __float2bfloat16(f.z); h.z = *(ushort*)&c;
        __hip_bfloat16 d = __float2bfloat16(f.w); h.w = *(ushort*)&d;
    }
    ((ushort4*)Eb)[idx] = h;
}

// ---------------------------------------------------------------------------
// Kernel 0b: per-batch inter-mask bitmap. maskTab[g][j/64] bit (j%64) = 1 iff
// batch[j] != g. 2 KB total.
// ---------------------------------------------------------------------------
__global__ __launch_bounds__(256) void build_mask(const int* __restrict__ batch,
                                                  unsigned long long* __restrict__ maskTab) {
    const int j = blockIdx.x * 256 + threadIdx.x;
    const int b = batch[j];
    const int wv = j >> 6;
#pragma unroll
    for (int g = 0; g < GG; ++g) {
        const unsigned long long m = __ballot(b != g);
        if ((threadIdx.x & 63) == 0) maskTab[g * (NN / 64) + wv] = m;
    }
}

// ---------------------------------------------------------------------------
// Kernel 1: sim = Eb @ Eb^T via MFMA bf16 -> bf16 out. 128x128 tile, 4 waves
// (2x2 of 64x64), 16x16x32 MFMA, BK=32. global_load_lds width=16 staging
// into unpadded [128][32] with XOR chunk swizzle (2-way max = free).
// Epilogue staged in 4 chunks of 32 rows through the 16 KB A/B buffers.
// ---------------------------------------------------------------------------
__global__ __launch_bounds__(256) void gemm_bf16(const ushort* __restrict__ Eb,
                                                 ushort* __restrict__ simb) {
    __shared__ union {
        struct { ushort A[128 * 32]; ushort B[128 * 32]; } s;  // 8 KB + 8 KB
        ushort stage[32 * 136];                                // 8.7 KB epilogue
    } lds;

    const int t = threadIdx.x;
    const int w = t >> 6, lane = t & 63;
    const int quad = lane >> 4, mr = lane & 15;
    const int rowBase = blockIdx.y * 128, colBase = blockIdx.x * 128;
    const int waveRow = (w & 1) * 64, waveCol = (w >> 1) * 64;

    const int lrow = lane >> 2;              // 0..15 row within 16-row slab
    const int lslot = lane & 3;              // LDS chunk slot
    const int gchunk = lslot ^ ((lrow >> 1) & 3);  // swizzled global chunk

    f32x4 acc[4][4];
#pragma unroll
    for (int a = 0; a < 4; ++a)
#pragma unroll
        for (int b = 0; b < 4; ++b) acc[a][b] = (f32x4)(0.0f);

    for (int kc = 0; kc < DD; kc += 32) {
#pragma unroll
        for (int n = 0; n < 2; ++n) {
            const int r = w * 32 + n * 16 + lrow;  // (r>>1)&3 == (lrow>>1)&3
            const ushort* ga = Eb + (size_t)(rowBase + r) * DD + kc + gchunk * 8;
            const ushort* gb = Eb + (size_t)(colBase + r) * DD + kc + gchunk * 8;
            async16(ga, &lds.s.A[(w * 32 + n * 16) * 32]);
            async16(gb, &lds.s.B[(w * 32 + n * 16) * 32]);
        }
        __syncthreads();

        const int swzF = (mr >> 1) & 3;
        bf16x8 af[4], bfr[4];
#pragma unroll
        for (int rt = 0; rt < 4; ++rt)
            af[rt] = *(const bf16x8*)&lds.s.A[(waveRow + rt * 16 + mr) * 32 +
                                              ((quad ^ swzF) * 8)];
#pragma unroll
        for (int ct = 0; ct < 4; ++ct)
            bfr[ct] = *(const bf16x8*)&lds.s.B[(waveCol + ct * 16 + mr) * 32 +
                                               ((quad ^ swzF) * 8)];
#pragma unroll
        for (int rt = 0; rt < 4; ++rt)
#pragma unroll
            for (int ct = 0; ct < 4; ++ct)
                acc[rt][ct] = __builtin_amdgcn_mfma_f32_16x16x32_bf16(
                    af[rt], bfr[ct], acc[rt][ct], 0, 0, 0);
        __syncthreads();
    }

    // epilogue: 4 chunks of 32 tile-rows through the 8.7 KB stage buffer
#pragma unroll
    for (int c = 0; c < 4; ++c) {
        __syncthreads();  // stage free (K-loop done / prev copy done)
        if ((w & 1) == (c >> 1)) {
            const int rtBase = 2 * (c & 1);
#pragma unroll
            for (int r2 = 0; r2 < 2; ++r2) {
                const int rt = rtBase + r2;
#pragma unroll
                for (int ct = 0; ct < 4; ++ct)
#pragma unroll
                    for (int reg = 0; reg < 4; ++reg) {
                        __hip_bfloat16 hb = __float2bfloat16(acc[rt][ct][reg]);
                        const int lr2 = r2 * 16 + quad * 4 + reg;  // 0..31
                        lds.stage[lr2 * 136 + waveCol + ct * 16 + mr] = *(ushort*)&hb;
                    }
            }
        }
        __syncthreads();
#pragma unroll
        for (int it = 0; it < 2; ++it) {
            const int cid = t + it * 256;   // 0..511 (32 rows x 16 int4)
            const int row = cid >> 4;
            const int off = (cid & 15) * 8;
            *(int4*)(simb + (size_t)(rowBase + c * 32 + row) * NN + colBase + off) =
                *(const int4*)&lds.stage[row * 136 + off];
        }
    }
}

// ---------------------------------------------------------------------------
// Kernel 2: ONE ROW PER BLOCK, 128 threads (2 waves share the row).
// This round: the coarse histogram is REPLICATED x4 by lane&3 (layout
// hist[bin][rep] -> replicas in 4 adjacent banks, conflict-free) to break the
// hot-bin same-address atomic serialization (sim ~ N(0,16^2) -> top byte
// lands in ~10 bins; 4096 atomics/block queued on the per-CU LDS pipe).
// A shfl-based merge phase folds replicas into merged[256] before the scan.
// Also emits a mutuality bitset (bits[i] row: bit j = "j in knn(i)") so
// finalize_k does a 1-load mutual test instead of a 30-load scan.
// ---------------------------------------------------------------------------
__global__ __launch_bounds__(128, 8) void select_rescore(
        const ushort* __restrict__ sim,
        const float* __restrict__ E,
        const int* __restrict__ batch,
        const unsigned long long* __restrict__ maskTab,
        int* __restrict__ knn,
        unsigned* __restrict__ bits) {
    __shared__ unsigned histS[1024];       // [bin][rep], rep = lane&3
    __shared__ unsigned mergedS[256];
    __shared__ unsigned subS[256];
    __shared__ int candIdxS[2][CAND_CAP];
    __shared__ double candValS[2][CAND_CAP];
    __shared__ int cntS[2];
    __shared__ int cbS[2];
    __shared__ unsigned remS[2];
    __shared__ unsigned thrS[2];

    const int t = threadIdx.x;
    const int w = t >> 6, lane = t & 63;
    const int rep = lane & 3;
    const int i = blockIdx.x;
    const int bi = batch[i];

#pragma unroll
    for (int z = 0; z < 8; ++z) histS[t + z * 128] = 0u;
    subS[t] = 0u; subS[t + 128] = 0u;
    if (t < 2) cntS[t] = 0;
    __syncthreads();

    // ---- pass 1: load 32 elems/thread, build keys + inter-mask + histogram --
    // element j = c*1024 + t*8 + e  (16 B / thread per chunk: fully coalesced)
    unsigned kp[16];                 // packed sortable keys (2 per u32)
    unsigned interm = 0;             // bit (c*8+e) => batch differs
    {
        const ushort* sp = sim + (size_t)i * NN + t * 8;
        const unsigned long long* mp = maskTab + bi * (NN / 64) + (t >> 3);
        const int sh = (t & 7) * 8;
#pragma unroll
        for (int c = 0; c < 4; ++c) {
            const int4 sv = *(const int4*)(sp + c * 1024);
            const unsigned mb = (unsigned)(mp[c * 16] >> sh) & 0xFFu;
            interm |= mb << (c * 8);
            const unsigned uu[4] = {(unsigned)sv.x, (unsigned)sv.y,
                                    (unsigned)sv.z, (unsigned)sv.w};
#pragma unroll
            for (int p = 0; p < 4; ++p) {
                const unsigned u = uu[p];
                const unsigned sgn = u & 0x80008000u;
                // per-half monotone transform: pos: ^0x8000, neg: ^0xFFFF
                const unsigned k2 = u ^ (0x80008000u | ((sgn >> 15) * 0x7FFFu));
                kp[c * 4 + p] = k2;
                const unsigned m0 = (mb >> (2 * p)) & 1u;
                const unsigned m1 = (mb >> (2 * p + 1)) & 1u;
                atomicAdd(&histS[(((k2 >> 8) & 0xFF) << 2) + rep], m0 ? 0x10000u : 1u);
                atomicAdd(&histS[((k2 >> 24) << 2) + rep], m1 ? 0x10000u : 1u);
            }
        }
    }
    __syncthreads();

    // ---- merge replicas: conflict-free coalesced reads + 4-lane shfl tree ----
#pragma unroll
    for (int k = 0; k < 8; ++k) {
        const int wd = t + 128 * k;          // word = bin*4 + rep
        unsigned v = histS[wd];
        v += __shfl_xor(v, 1);
        v += __shfl_xor(v, 2);
        if ((lane & 3) == 0) mergedS[wd >> 2] = v;
    }
    __syncthreads();

    // ---- pass 2: packed descending scan over coarse bins (redundant per
    // wave -- both waves compute identical values from merged hist) ----
    {
        const unsigned* hb = &mergedS[lane * 4];
        const unsigned s4 = hb[0] + hb[1] + hb[2] + hb[3];
        unsigned suf = s4;  // suffix-inclusive over lanes >= lane (higher bins)
#pragma unroll
        for (int off = 1; off < 64; off <<= 1) {
            const unsigned o = __shfl_down(suf, off);
            if (lane + off < 64) suf += o;
        }
        unsigned cum = suf - s4;  // count in bins above this lane's range
#pragma unroll
        for (int b = 3; b >= 0; --b) {
            const unsigned h = hb[b];
            const unsigned prev = cum;
            cum += h;
            if ((cum & 0xFFFFu) >= TGT_INTRA && (prev & 0xFFFFu) < TGT_INTRA) {
                cbS[0] = lane * 4 + b;
                remS[0] = TGT_INTRA - (prev & 0xFFFFu);
            }
            if ((cum >> 16) >= TGT_INTER && (prev >> 16) < TGT_INTER) {
                cbS[1] = lane * 4 + b;
                remS[1] = TGT_INTER - (prev >> 16);
            }
        }
    }
    __syncthreads();

    // ---- pass 2b: sub-histogram of crossing bins (low byte; near-uniform
    // mantissa bits -> no replication needed) ----
    {
        const int cb0 = cbS[0], cb1 = cbS[1];
#pragma unroll
        for (int c = 0; c < 4; ++c)
#pragma unroll
            for (int p = 0; p < 4; ++p) {
                const unsigned k2 = kp[c * 4 + p];
                const unsigned k0 = k2 & 0xFFFFu, k1 = k2 >> 16;
                const int m0 = (interm >> (c * 8 + 2 * p)) & 1;
                const int m1 = (interm >> (c * 8 + 2 * p + 1)) & 1;
                if ((int)(k0 >> 8) == (m0 ? cb1 : cb0))
                    atomicAdd(&subS[k0 & 0xFF], m0 ? 0x10000u : 1u);
                if ((int)(k1 >> 8) == (m1 ? cb1 : cb0))
                    atomicAdd(&subS[k1 & 0xFF], m1 ? 0x10000u : 1u);
            }
    }
    __syncthreads();

    // ---- pass 2c: scan sub-bins -> exact 16-bit thresholds (redundant) ----
    {
        const unsigned rI = remS[0], rT = remS[1];
        const int cb0 = cbS[0], cb1 = cbS[1];
        const unsigned* sb = &subS[lane * 4];
        const unsigned s4 = sb[0] + sb[1] + sb[2] + sb[3];
        unsigned suf = s4;
#pragma unroll
        for (int off = 1; off < 64; off <<= 1) {
            const unsigned o = __shfl_down(suf, off);
            if (lane + off < 64) suf += o;
        }
        unsigned cum = suf - s4;
#pragma unroll
        for (int b = 3; b >= 0; --b) {
            const unsigned h = sb[b];
            const unsigned prev = cum;
            cum += h;
            if ((cum & 0xFFFFu) >= rI && (prev & 0xFFFFu) < rI)
                thrS[0] = ((unsigned)cb0 << 8) | (unsigned)(lane * 4 + b);
            if ((cum >> 16) >= rT && (prev >> 16) < rT)
                thrS[1] = ((unsigned)cb1 << 8) | (unsigned)(lane * 4 + b);
        }
    }
    __syncthreads();

    // ---- pass 3: collect candidate indices ----
    {
        const unsigned thr0 = thrS[0], thr1 = thrS[1];
#pragma unroll
        for (int c = 0; c < 4; ++c)
#pragma unroll
            for (int p = 0; p < 4; ++p) {
                const unsigned k2 = kp[c * 4 + p];
                const unsigned k0 = k2 & 0xFFFFu, k1 = k2 >> 16;
                const int m0 = (interm >> (c * 8 + 2 * p)) & 1;
                const int m1 = (interm >> (c * 8 + 2 * p + 1)) & 1;
                if (k0 >= (m0 ? thr1 : thr0)) {
                    const int pos = atomicAdd(&cntS[m0], 1);
                    if (pos < CAND_CAP) candIdxS[m0][pos] = c * 1024 + t * 8 + 2 * p;
                }
                if (k1 >= (m1 ? thr1 : thr0)) {
                    const int pos = atomicAdd(&cntS[m1], 1);
                    if (pos < CAND_CAP) candIdxS[m1][pos] = c * 1024 + t * 8 + 2 * p + 1;
                }
            }
    }
    __syncthreads();

    // ---- pass 4: fp64 rescore, 128-wide (tot <= 128 -> one pass);
    // E[i] is block-uniform -> scalar loads ----
    const int c0 = min(cntS[0], CAND_CAP);
    const int c1 = min(cntS[1], CAND_CAP);
    {
        const int tot = c0 + c1;
        const float* ei = E + (size_t)i * DD;
        if (t < tot) {
            const int m = (t < c0) ? 0 : 1;
            const int s = m ? (t - c0) : t;
            const int j = candIdxS[m][s];
            const float* ej = E + (size_t)j * DD;
            double a0 = 0, a1 = 0, a2 = 0, a3 = 0;
#pragma unroll 8
            for (int k = 0; k < DD; k += 4) {
                const float4 e = *(const float4*)(ej + k);
                a0 = fma((double)ei[k + 0], (double)e.x, a0);
                a1 = fma((double)ei[k + 1], (double)e.y, a1);
                a2 = fma((double)ei[k + 2], (double)e.z, a2);
                a3 = fma((double)ei[k + 3], (double)e.w, a3);
            }
            candValS[m][s] = (a0 + a1) + (a2 + a3);
        }
    }
    __syncthreads();

    // ---- pass 5: rank-based ordered output (ties: lower index first);
    // wave 0 ranks intra, wave 1 ranks inter (parallel). Also set the
    // out-edge bit i->idx for the O(1) mutuality test in finalize_k. ----
    if (w == 0) {
        if (lane < c0) {
            const double v = candValS[0][lane];
            const int idx = candIdxS[0][lane];
            int r = 0;
            for (int s = 0; s < c0; ++s) {
                const double o = candValS[0][s];
                const int oi = candIdxS[0][s];
                r += (o > v) || (o == v && oi < idx);
            }
            if (r >= 1 && r <= 20) {  // rank0 = self, dropped
                knn[i * K_TOT + r - 1] = idx;
                atomicOr(&bits[((size_t)i << 7) + (idx >> 5)], 1u << (idx & 31));
            }
        }
    } else {
        if (lane < c1) {
            const double v = candValS[1][lane];
            const int idx = candIdxS[1][lane];
            int r = 0;
            for (int s = 0; s < c1; ++s) {
                const double o = candValS[1][s];
                const int oi = candIdxS[1][s];
                r += (o > v) || (o == v && oi < idx);
            }
            if (r < 10) {
                knn[i * K_TOT + 20 + r] = idx;
                atomicOr(&bits[((size_t)i << 7) + (idx >> 5)], 1u << (idx & 31));
            }
        }
    }
}

// ---------------------------------------------------------------------------
// Kernel 3: mutuality via bitset (1 L2-hot load, was a 30-load scan) +
// sparse locality scatter + all_close.
// ---------------------------------------------------------------------------
__global__ __launch_bounds__(256) void finalize_k(const int* __restrict__ knn,
                                                  const unsigned* __restrict__ bits,
                                                  const float* __restrict__ adj,
                                                  const int* __restrict__ cl,
                                                  float* __restrict__ out) {
    const int gid = blockIdx.x * 256 + threadIdx.x;
    if (gid >= NN * K_TOT) return;
    const int i = gid / K_TOT;
    const int j = knn[gid];

    // mutual(i,j) = j in knn(i) [by construction] && i in knn(j)
    const bool mutual = (bits[((size_t)j << 7) + (i >> 5)] >> (i & 31)) & 1u;

    if (mutual) out[(size_t)i * NN + j] = adj[(size_t)i * NN + j];

    bool ac = mutual;
    if (!ac) {
        bool alleq = true;
#pragma unroll
        for (int m = 0; m < MM; ++m) alleq &= (cl[m * NN + i] == cl[m * NN + j]);
        ac = alleq;
    }
    out[(size_t)NN * NN + gid] = ac ? 1.0f : 0.0f;
}

// ---------------------------------------------------------------------------
extern "C" void kernel_launch(void* const* d_in, const int* in_sizes, int n_in,
                              void* d_out, int out_size, void* d_ws, size_t ws_size,
                              hipStream_t stream) {
    const float* adj = (const float*)d_in[0];
    const float* enc = (const float*)d_in[1];
    const int* batch = (const int*)d_in[2];
    const int* cl = (const int*)d_in[3];
    float* out = (float*)d_out;

    const size_t simB = (size_t)NN * NN * sizeof(ushort);   // 33.6 MB
    const size_t ebB = (size_t)NN * DD * sizeof(ushort);    // 2.1 MB
    const size_t knnB = (size_t)NN * K_TOT * sizeof(int);   // 0.49 MB
    const size_t maskB = (size_t)GG * (NN / 64) * sizeof(unsigned long long); // 2 KB
    const size_t bitsB = (size_t)NN * (NN / 8);             // 2 MB mutuality bitset

    const dim3 gGrid(NN / 128, NN / 128);

    if (ws_size >= simB + ebB + knnB + maskB + bitsB) {
        ushort* simb = (ushort*)d_ws;
        ushort* Eb = (ushort*)((char*)d_ws + simB);
        int* knn = (int*)((char*)d_ws + simB + ebB);
        unsigned long long* maskTab =
            (unsigned long long*)((char*)d_ws + simB + ebB + knnB);
        unsigned* bits = (unsigned*)((char*)d_ws + simB + ebB + knnB + maskB);
        hipMemsetAsync(d_out, 0, (size_t)NN * NN * sizeof(float), stream);
        hipMemsetAsync(bits, 0, bitsB, stream);
        convert_bf16<<<NN * DD / 4 / 256, 256, 0, stream>>>(enc, Eb);
        build_mask<<<NN / 256, 256, 0, stream>>>(batch, maskTab);
        gemm_bf16<<<gGrid, 256, 0, stream>>>(Eb, simb);
        select_rescore<<<NN, 128, 0, stream>>>(simb, enc, batch, maskTab, knn, bits);
        finalize_k<<<(NN * K_TOT + 255) / 256, 256, 0, stream>>>(knn, bits, adj, cl, out);
    } else {
        // fallback: stage bf16 sims in the locality region of d_out, memset after
        ushort* simb = (ushort*)d_out;
        ushort* Eb = (ushort*)d_ws;
        int* knn = (int*)((char*)d_ws + ebB);
        unsigned long long* maskTab =
            (unsigned long long*)((char*)d_ws + ebB + knnB);
        unsigned* bits = (unsigned*)((char*)d_ws + ebB + knnB + maskB);
        convert_bf16<<<NN * DD / 4 / 256, 256, 0, stream>>>(enc, Eb);
        build_mask<<<NN / 256, 256, 0, stream>>>(batch, maskTab);
        hipMemsetAsync(bits, 0, bitsB, stream);
        gemm_bf16<<<gGrid, 256, 0, stream>>>(Eb, simb);
        select_rescore<<<NN, 128, 0, stream>>>(simb, enc, batch, maskTab, knn, bits);
        hipMemsetAsync(d_out, 0, (size_t)NN * NN * sizeof(float), stream);
        finalize_k<<<(NN * K_TOT + 255) / 256, 256, 0, stream>>>(knn, bits, adj, cl, out);
    }
}